// Round 11
// baseline (176.979 us; speedup 1.0000x reference)
//
#include <hip/hip_runtime.h>
#include <hip/hip_bf16.h>

typedef unsigned short u16;
typedef unsigned int u32;
typedef __attribute__((ext_vector_type(8))) short short8;   // 8 bf16 = 4 VGPRs
typedef __attribute__((ext_vector_type(4))) float f32x4;
typedef __attribute__((ext_vector_type(4))) u32 u32x4;

#define MFMA16(a, b, c) __builtin_amdgcn_mfma_f32_16x16x32_bf16((a), (b), (c), 0, 0, 0)
#define S8(v) __builtin_bit_cast(short8, (v))
#define SBAR() __builtin_amdgcn_sched_barrier(0)

__device__ __forceinline__ u32 pack2(float a, float b) {
    union { __hip_bfloat162 h; u32 u; } v;
    v.h = __float22bfloat162_rn(make_float2(a, b));   // x->lo, y->hi
    return v.u;
}
__device__ __forceinline__ u16 f2b(float f) {
    union { float f; u32 i; } v; v.f = f;
    u32 x = v.i;
    return (u16)((x + 0x7FFFu + ((x >> 16) & 1u)) >> 16);
}

__device__ __forceinline__ void gl_lds16(const u16* g, u16* l) {
    __builtin_amdgcn_global_load_lds(
        (const __attribute__((address_space(1))) void*)g,
        (__attribute__((address_space(3))) void*)l, 16, 0, 0);
}

// ---- prep: weights -> wave-order A-fragment layout in d_ws -----------------
__global__ void wt_prep(const float* __restrict__ vW2, const float* __restrict__ cW2,
                        const float* __restrict__ W1f, const float* __restrict__ W2f,
                        const float* __restrict__ W3f, u16* __restrict__ wt) {
    int i = blockIdx.x * 256 + threadIdx.x;          // 5*16384 elements
    if (i >= 5 * 16384) return;
    int l = i >> 14, e = i & 16383;
    int fr = e >> 9, lane = (e >> 3) & 63, j = e & 7;
    int ot = fr >> 2, ks = fr & 3;
    int c = lane & 15, q = lane >> 4;
    int f = 32 * ks + 16 * (j >> 2) + 4 * q + (j & 3);
    const float* src = (l == 0) ? vW2 : (l == 1) ? cW2 : (l == 2) ? W1f
                     : (l == 3) ? W2f : W3f;
    wt[i] = f2b(src[f * 128 + ot * 16 + c]);
}

// ---- round 21: OCCUPANCY (4 waves/SIMD) via 32-ROW WAVES --------------------
// R10 datum: global-path R3 and LDS-path R10 land at IDENTICAL 90 us / 36%
// MfmaUtil / 18.5% occupancy -> weight path was never the limiter. Invariant:
// ~1.5 waves/SIMD. Accounting closes as latency-bound at 2-wave cap; the cap
// is register arithmetic: 64-row waves need 128 activation regs alone ->
// ~200+ unified -> 2 waves/SIMD since round 0.
// Fix: 32-row waves. Regs: act 64 (ping+pong) + wt 16 (single half-buffer) +
// acc 16 + misc ~15 = ~115 <= 128 -> 4 waves/SIMD (waves_per_eu(4)). Blocks =
// 512 thd (8 waves, 256 rows) amortize a 66 KB LDS budget -> 2 blocks/CU =
// 16 waves/CU. TLP is now the latency hider (so single-buffer weight reads
// are fine). ALL 4 layers LDS-staged: grid split into PURE con / var blocks
// (block-uniform table choice); biases+W4 staged to LDS (they were L1-evicted
// by weight streams). LDS-port roofline ~80 B/cyc vs 85 ceiling -> ~48 us.

// Stage one 32 KB layer into LDS buffer B (8 waves x 4 x 1 KB).
#define STAGE(LSRC, B) do {                                                   \
    _Pragma("unroll")                                                         \
    for (int r = 0; r < 4; ++r) {                                             \
        int ch = r * 8 + wv;                                                  \
        gl_lds16(WT + (size_t)(LSRC) * 16384 + ch * 512 + lane * 8,           \
                 ldsw + (B) * 16384 + ch * 512);                              \
    } } while (0)

// Read HALF-quarter (4 frags) of quarter QQ from LDS buf B into wu0..3:
// H=0 -> frags {8Q+0,8Q+1,8Q+4,8Q+5} (= {lo k0, lo k1, hi k0, hi k1});
// H=1 -> frags {8Q+2,8Q+3,8Q+6,8Q+7} (k2,k3).
#define LDSH(B, QQ, H) do {                                                   \
    const u16* _lp = ldsw + (B) * 16384 + ((QQ) * 8 + (H) * 2) * 512 + lane * 8; \
    wu0 = *(const short8*)(_lp + 0 * 512);                                    \
    wu1 = *(const short8*)(_lp + 1 * 512);                                    \
    wu2 = *(const short8*)(_lp + 4 * 512);                                    \
    wu3 = *(const short8*)(_lp + 5 * 512);                                    \
} while (0)

// Quarter bias from the LDS bias area (layer LB, quarter QQ).
#define BIVL(LB, QQ) do {                                                     \
    biv0 = *(const f32x4*)(ldsb + (LB) * 128 + ((QQ) * 2 + 0) * 16 + q * 4);  \
    biv1 = *(const f32x4*)(ldsb + (LB) * 128 + ((QQ) * 2 + 1) * 16 + q * 4);  \
} while (0)

// k0 (bias as C) + k1 on 4 chains (2 col-tiles x 2 row-tiles).
#define HALF0(I) do {                                                         \
    ac00 = MFMA16(wu0, S8(I##_r0_k0), biv0);                                  \
    ac01 = MFMA16(wu0, S8(I##_r1_k0), biv0);                                  \
    ac10 = MFMA16(wu2, S8(I##_r0_k0), biv1);                                  \
    ac11 = MFMA16(wu2, S8(I##_r1_k0), biv1);                                  \
    ac00 = MFMA16(wu1, S8(I##_r0_k1), ac00);                                  \
    ac01 = MFMA16(wu1, S8(I##_r1_k1), ac01);                                  \
    ac10 = MFMA16(wu3, S8(I##_r0_k1), ac10);                                  \
    ac11 = MFMA16(wu3, S8(I##_r1_k1), ac11);                                  \
} while (0)

// k2 + k3.
#define HALF1(I) do {                                                         \
    ac00 = MFMA16(wu0, S8(I##_r0_k2), ac00);                                  \
    ac01 = MFMA16(wu0, S8(I##_r1_k2), ac01);                                  \
    ac10 = MFMA16(wu2, S8(I##_r0_k2), ac10);                                  \
    ac11 = MFMA16(wu2, S8(I##_r1_k2), ac11);                                  \
    ac00 = MFMA16(wu1, S8(I##_r0_k3), ac00);                                  \
    ac01 = MFMA16(wu1, S8(I##_r1_k3), ac01);                                  \
    ac10 = MFMA16(wu3, S8(I##_r0_k3), ac10);                                  \
    ac11 = MFMA16(wu3, S8(I##_r1_k3), ac11);                                  \
} while (0)

#define EPI(RELU, ACC, OUT, C0, C1)                                           \
  { float v0 = ACC[0], v1 = ACC[1], v2 = ACC[2], v3 = ACC[3];                 \
    if (RELU) { v0 = fmaxf(v0, 0.f); v1 = fmaxf(v1, 0.f);                     \
                v2 = fmaxf(v2, 0.f); v3 = fmaxf(v3, 0.f); }                   \
    OUT.C0 = pack2(v0, v1); OUT.C1 = pack2(v2, v3); }

// Quarter QQ of a 128->128 layer from LDS buf B, bias set LB.
#define QUARTER(B, LB, I, O, QQ, RELU) do {                                   \
    BIVL(LB, QQ);                                                             \
    LDSH(B, QQ, 0);                                                           \
    HALF0(I);                                                                 \
    LDSH(B, QQ, 1);                                                           \
    HALF1(I);                                                                 \
    EPI(RELU, ac00, O##_r0_k##QQ, x, y)                                       \
    EPI(RELU, ac01, O##_r1_k##QQ, x, y)                                       \
    EPI(RELU, ac10, O##_r0_k##QQ, z, w)                                       \
    EPI(RELU, ac11, O##_r1_k##QQ, z, w)                                       \
} while (0)

#define LAYER(B, LB, I, O, RELU)                                              \
    QUARTER(B, LB, I, O, 0, RELU);                                            \
    QUARTER(B, LB, I, O, 1, RELU);                                            \
    QUARTER(B, LB, I, O, 2, RELU);                                            \
    QUARTER(B, LB, I, O, 3, RELU);

// Final-layer quarter: relu + fused W4 dot (W4 from LDS bias area, off 512).
#define QUARTER_LAST(B, I, QQ) do {                                           \
    BIVL(3, QQ);                                                              \
    f32x4 ww0 = *(const f32x4*)(ldsb + 512 + ((QQ) * 2 + 0) * 16 + q * 4);    \
    f32x4 ww1 = *(const f32x4*)(ldsb + 512 + ((QQ) * 2 + 1) * 16 + q * 4);    \
    LDSH(B, QQ, 0);                                                           \
    HALF0(I);                                                                 \
    LDSH(B, QQ, 1);                                                           \
    HALF1(I);                                                                 \
    pd0 += fmaxf(ac00[0], 0.f) * ww0[0] + fmaxf(ac00[1], 0.f) * ww0[1]        \
         + fmaxf(ac00[2], 0.f) * ww0[2] + fmaxf(ac00[3], 0.f) * ww0[3];       \
    pd0 += fmaxf(ac10[0], 0.f) * ww1[0] + fmaxf(ac10[1], 0.f) * ww1[1]        \
         + fmaxf(ac10[2], 0.f) * ww1[2] + fmaxf(ac10[3], 0.f) * ww1[3];       \
    pd1 += fmaxf(ac01[0], 0.f) * ww0[0] + fmaxf(ac01[1], 0.f) * ww0[1]        \
         + fmaxf(ac01[2], 0.f) * ww0[2] + fmaxf(ac01[3], 0.f) * ww0[3];       \
    pd1 += fmaxf(ac11[0], 0.f) * ww1[0] + fmaxf(ac11[1], 0.f) * ww1[1]        \
         + fmaxf(ac11[2], 0.f) * ww1[2] + fmaxf(ac11[3], 0.f) * ww1[3];       \
} while (0)

// ---- phase 0: vW1/cW1 [2->128] + relu, f32 VALU, pi-slot packing -----------
#define P0_ROW(V, C0, C1, I0, I1)                                             \
  { float x0 = fmaxf(fmaf(I0, wA.x, fmaf(I1, wB.x, bz.x)), 0.f);              \
    float x1 = fmaxf(fmaf(I0, wA.y, fmaf(I1, wB.y, bz.y)), 0.f);              \
    float x2 = fmaxf(fmaf(I0, wA.z, fmaf(I1, wB.z, bz.z)), 0.f);              \
    float x3 = fmaxf(fmaf(I0, wA.w, fmaf(I1, wB.w, bz.w)), 0.f);              \
    V.C0 = pack2(x0, x1); V.C1 = pack2(x2, x3); }

#define P0_HI(KS, HI, C0, C1)                                                 \
  { const int base = (KS) * 32 + (HI) * 16 + q * 4;                           \
    float4 wA = *(const float4*)(w1p + base);                                 \
    float4 wB = *(const float4*)(w1p + 128 + base);                           \
    float4 bz = *(const float4*)(b1p + base);                                 \
    P0_ROW(a_r0_k##KS, C0, C1, in00, in10)                                    \
    P0_ROW(a_r1_k##KS, C0, C1, in01, in11) }

#define P0_KS(KS) P0_HI(KS, 0, x, y) P0_HI(KS, 1, z, w)

#define P0_IN(RT, I0, I1)                                                     \
  { int g = rowW + (RT) * 16 + c; I0 = 0.f; I1 = 0.f;                         \
    if (g < limit) { float2 t2 = *(const float2*)(fb + 2 * g); I0 = t2.x; I1 = t2.y; } }

// ---- fused MLP: 512 threads = 8 waves x 32 rows = 256 rows/block -----------
// Pure con/var blocks (block-uniform table select). All 4 layers from LDS.
__global__ __attribute__((amdgpu_flat_work_group_size(512, 512),
                          amdgpu_waves_per_eu(4))) void
mlp_fused(
    const float* __restrict__ varf, const float* __restrict__ conf,
    const float* __restrict__ vW1, const float* __restrict__ vb1, const float* __restrict__ vb2,
    const float* __restrict__ cW1, const float* __restrict__ cb1, const float* __restrict__ cb2,
    const float* __restrict__ b1,  const float* __restrict__ b2,  const float* __restrict__ b3,
    const float* __restrict__ W4,  const float* __restrict__ b4,
    const u16* __restrict__ WT,   float* __restrict__ out,
    int n_var, int n_con, int nb_con)
{
    const int t = threadIdx.x;          // 0..511
    const int lane = t & 63, wv = t >> 6;          // wave 0..7
    const int c = lane & 15, q = lane >> 4;
    const int bid = blockIdx.x;
    const bool use_con = (bid < nb_con);           // block-uniform
    const int row0 = use_con ? bid * 256 : n_con + (bid - nb_con) * 256;
    const int rowW = row0 + wv * 32;    // wave's base row (32 rows per wave)
    const int limit = use_con ? n_con : n_var;     // feature+store bound

    __shared__ u16 ldsw[2 * 16384];     // 2 x 32 KB weight double-buffer
    __shared__ float ldsb[640];         // biases bs0,b1,b2,b3 + W4

    // ---- named SSA state (~115 unified regs peak) ----
    u32x4 a_r0_k0, a_r0_k1, a_r0_k2, a_r0_k3;
    u32x4 a_r1_k0, a_r1_k1, a_r1_k2, a_r1_k3;
    u32x4 b_r0_k0, b_r0_k1, b_r0_k2, b_r0_k3;
    u32x4 b_r1_k0, b_r1_k1, b_r1_k2, b_r1_k3;
    short8 wu0, wu1, wu2, wu3;          // single weight half-buffer
    f32x4 biv0, biv1;
    f32x4 ac00, ac01, ac10, ac11;

    const float* bs0 = use_con ? cb2 : vb2;

    // stage layer-0 table (per-block con/var) + W1; biases to LDS
    STAGE((use_con ? 1 : 0), 0);        // L0 -> buf0
    STAGE(2, 1);                        // W1 -> buf1
    {   // biases: ldsb[0..512) = {bs0,b1,b2,b3}, [512..640) = W4
        int which = t >> 7, idx = t & 127;
        const float* p = (which == 0) ? bs0 : (which == 1) ? b1
                       : (which == 2) ? b2 : b3;
        ldsb[t >= 512 ? 0 : t] = (t >= 512) ? ldsb[0] : p[idx];  // t<512 only
        if (t < 128) ldsb[512 + t] = W4[t];
    }
    SBAR();

    {
        const float* w1p = use_con ? cW1 : vW1;    // [2][128]
        const float* b1p = use_con ? cb1 : vb1;
        const float* fb  = use_con ? conf : varf;
        float in00, in01, in10, in11;
        P0_IN(0, in00, in10) P0_IN(1, in01, in11)
        P0_KS(0) P0_KS(1) P0_KS(2) P0_KS(3)
    }

    float pd0 = 0.f, pd1 = 0.f;

    __syncthreads();                 // L0(buf0)+W1(buf1)+biases landed

    // ---------- layer 0: vW2/cW2 (no relu) from buf0 ------------------------
    LAYER(0, 0, a, b, 0)
    __syncthreads();                 // buf0 reads done
    STAGE(3, 0);  SBAR();            // W2 -> buf0 under layer-1 compute

    // ---------- layer 1: W1 (+relu) from buf1 -------------------------------
    LAYER(1, 1, b, a, 1)
    __syncthreads();                 // W2 landed; buf1 reads done
    STAGE(4, 1);  SBAR();            // W3 -> buf1 under layer-2 compute

    // ---------- layer 2: W2 (+relu) from buf0 -------------------------------
    LAYER(0, 2, a, b, 1)
    __syncthreads();                 // W3 landed; buf0 free

    // ---------- layer 3: W3 (+relu, W4 fused) from buf1 ---------------------
    QUARTER_LAST(1, b, 0);
    QUARTER_LAST(1, b, 1);
    QUARTER_LAST(1, b, 2);
    QUARTER_LAST(1, b, 3);

    // ---------- reduce across quads (disjoint outf sets), sigmoid, store ----
    float bias4 = b4[0];
#define REDUCE(PD, RT)                                                        \
    { float v = PD;                                                           \
      v += __shfl_xor(v, 16);                                                 \
      v += __shfl_xor(v, 32);                                                 \
      if (q == 0) {                                                           \
          int g = rowW + (RT) * 16 + c;                                       \
          if (g < limit) out[g] = 1.f / (1.f + __expf(-(v + bias4)));         \
      } }
    REDUCE(pd0, 0) REDUCE(pd1, 1)
#undef REDUCE
}

extern "C" void kernel_launch(void* const* d_in, const int* in_sizes, int n_in,
                              void* d_out, int out_size, void* d_ws, size_t ws_size,
                              hipStream_t stream) {
    const float* varf = (const float*)d_in[0];
    const float* conf = (const float*)d_in[1];
    // d_in[2..4]: node_types / assoc_var / assoc_con — identity mapping, unused
    const float* vW1 = (const float*)d_in[5];
    const float* vb1 = (const float*)d_in[6];
    const float* vW2 = (const float*)d_in[7];
    const float* vb2 = (const float*)d_in[8];
    const float* cW1 = (const float*)d_in[9];
    const float* cb1 = (const float*)d_in[10];
    const float* cW2 = (const float*)d_in[11];
    const float* cb2 = (const float*)d_in[12];
    const float* W1  = (const float*)d_in[13];
    const float* b1  = (const float*)d_in[14];
    const float* W2  = (const float*)d_in[15];
    const float* b2  = (const float*)d_in[16];
    const float* W3  = (const float*)d_in[17];
    const float* b3  = (const float*)d_in[18];
    const float* W4  = (const float*)d_in[19];
    const float* b4  = (const float*)d_in[20];

    int n_var = in_sizes[0] / 2;       // 600000
    int n_con = in_sizes[1] / 2;       // 400000
    u16* wt = (u16*)d_ws;              // 5*16384*2 = 160 KB scratch

    hipLaunchKernelGGL(wt_prep, dim3(320), dim3(256), 0, stream,
                       vW2, cW2, W1, W2, W3, wt);

    int nb_con = (n_con + 255) / 256;              // 1563 pure-con blocks
    int nb_var = (n_var - n_con + 255) / 256;      // 782 pure-var blocks
    hipLaunchKernelGGL(mlp_fused, dim3(nb_con + nb_var), dim3(512), 0, stream,
                       varf, conf, vW1, vb1, vb2, cW1, cb1, cb2,
                       b1, b2, b3, W4, b4, wt, (float*)d_out, n_var, n_con,
                       nb_con);
}